// Round 1
// baseline (334.658 us; speedup 1.0000x reference)
//
#include <hip/hip_runtime.h>
#include <hip/hip_bf16.h>

// ---------------- types ----------------
typedef __bf16 bf16x8 __attribute__((ext_vector_type(8)));
typedef __bf16 bf16x4 __attribute__((ext_vector_type(4)));
typedef float  f32x4  __attribute__((ext_vector_type(4)));

__device__ __forceinline__ __bf16 to_bf16(float f) {
    __hip_bfloat16 h = __float2bfloat16(f);
    return *reinterpret_cast<__bf16*>(&h);
}

// ---------------- constants ----------------
// B=2, L=2048, DIM=1024, H=16, KVH=4, HD=64, REP=4
// qkv_raw row layout: [0,1024) q heads, [1024,1280) k heads, [1280,1536) v heads

// ---------------- weight transpose: src[K=1024][N] f32 -> dst[N][1024] bf16 ----
__global__ __launch_bounds__(256) void transpose_k(const float* __restrict__ src,
                                                   __bf16* __restrict__ dst, int N) {
    __shared__ float tile[32][33];
    int k0 = blockIdx.x * 32, n0 = blockIdx.y * 32;
    int tx = threadIdx.x & 31, ty = threadIdx.x >> 5;  // 32 x 8
#pragma unroll
    for (int r = 0; r < 4; ++r) {
        int kk = ty + r * 8;
        tile[kk][tx] = src[(size_t)(k0 + kk) * N + n0 + tx];
    }
    __syncthreads();
#pragma unroll
    for (int r = 0; r < 4; ++r) {
        int nn = ty + r * 8;
        dst[(size_t)(n0 + nn) * 1024 + k0 + tx] = to_bf16(tile[tx][nn]);
    }
}

// ---------------- GEMM: C[M][N] = A[M][K] * B[K][N], BT given as [N][K] bf16 ----
// 128x128 tile, BK=32, 4 waves (2x2), each wave 64x64 = 4x4 tiles of 16x16x32 MFMA.
template <bool AFP32>
__global__ __launch_bounds__(256) void gemm_bf16_k(const void* __restrict__ Av,
                                                   const __bf16* __restrict__ BT,
                                                   float* __restrict__ C,
                                                   int K, int N) {
    __shared__ __bf16 lA[128][40];  // +8 pad: conflict-free b128 frag reads
    __shared__ __bf16 lB[128][40];
    int tid = threadIdx.x;
    int m0 = blockIdx.x * 128;
    int n0 = blockIdx.y * 128;
    int wid = tid >> 6, lane = tid & 63;
    int wm = (wid >> 1) * 64, wn = (wid & 1) * 64;
    int lm = lane & 15, qd = lane >> 4;

    f32x4 acc[4][4] = {};

    for (int k0 = 0; k0 < K; k0 += 32) {
        if (AFP32) {
            const float* A = (const float*)Av;
#pragma unroll
            for (int it = 0; it < 4; ++it) {
                int chunk = tid + it * 256;      // 0..1023
                int row = chunk >> 3, c4 = chunk & 7;
                f32x4 v = *(const f32x4*)(A + (size_t)(m0 + row) * K + k0 + c4 * 4);
                bf16x4 h;
                h.x = to_bf16(v.x); h.y = to_bf16(v.y);
                h.z = to_bf16(v.z); h.w = to_bf16(v.w);
                *(bf16x4*)&lA[row][c4 * 4] = h;
            }
        } else {
            const __bf16* A = (const __bf16*)Av;
#pragma unroll
            for (int it = 0; it < 2; ++it) {
                int chunk = tid + it * 256;      // 0..511
                int row = chunk >> 2, c8 = chunk & 3;
                *(bf16x8*)&lA[row][c8 * 8] =
                    *(const bf16x8*)(A + (size_t)(m0 + row) * K + k0 + c8 * 8);
            }
        }
#pragma unroll
        for (int it = 0; it < 2; ++it) {
            int chunk = tid + it * 256;
            int row = chunk >> 2, c8 = chunk & 3;
            *(bf16x8*)&lB[row][c8 * 8] =
                *(const bf16x8*)(BT + (size_t)(n0 + row) * K + k0 + c8 * 8);
        }
        __syncthreads();

        bf16x8 af[4], bfr[4];
#pragma unroll
        for (int t = 0; t < 4; ++t) {
            af[t]  = *(const bf16x8*)&lA[wm + t * 16 + lm][qd * 8];
            bfr[t] = *(const bf16x8*)&lB[wn + t * 16 + lm][qd * 8];
        }
#pragma unroll
        for (int ti = 0; ti < 4; ++ti)
#pragma unroll
            for (int tj = 0; tj < 4; ++tj)
                acc[ti][tj] = __builtin_amdgcn_mfma_f32_16x16x32_bf16(
                    af[ti], bfr[tj], acc[ti][tj], 0, 0, 0);
        __syncthreads();
    }

    // C/D layout (verified m89/m91): col = lane&15, row = (lane>>4)*4 + reg
#pragma unroll
    for (int ti = 0; ti < 4; ++ti)
#pragma unroll
        for (int tj = 0; tj < 4; ++tj)
#pragma unroll
            for (int r = 0; r < 4; ++r) {
                int row = m0 + wm + ti * 16 + qd * 4 + r;
                int col = n0 + wn + tj * 16 + lm;
                C[(size_t)row * N + col] = acc[ti][tj][r];
            }
}

// ---------------- RMSNorm + RoPE (in place on qkv_raw), wave per (token, head) ----
__global__ __launch_bounds__(256) void norm_rope_k(float* __restrict__ qkv,
                                                   const float* __restrict__ gq,
                                                   const float* __restrict__ gk) {
    int w = blockIdx.x * 4 + (threadIdx.x >> 6);  // 0..81919 (4096 tokens * 20 heads)
    int lane = threadIdx.x & 63;
    int t = w / 20, hs = w % 20;
    int pos = t & 2047;
    bool isq = hs < 16;
    int col0 = isq ? hs * 64 : 1024 + (hs - 16) * 64;
    float g = isq ? gq[lane] : gk[lane];
    float* p = qkv + (size_t)t * 1536 + col0;
    float v = p[lane];
    float ss = v * v;
#pragma unroll
    for (int o = 32; o; o >>= 1) ss += __shfl_xor(ss, o);
    float scale = rsqrtf(ss * (1.0f / 64.0f) + 1e-6f);
    v = v * scale * g;
    // interleaved RoPE: pair (2i, 2i+1)
    int i2 = lane >> 1;
    float ex = (float)(2 * i2) * (1.0f / 64.0f);
    float inv = expf(-ex * 9.210340371976184f);  // theta^-(2i/64), theta=1e4
    float ang = (float)pos * inv;
    float c = cosf(ang), s = sinf(ang);
    float pv = __shfl_xor(v, 1);
    float out = (lane & 1) ? (pv * s + v * c) : (v * c - pv * s);
    p[lane] = out;
}

// ---------------- flash attention ----------------
// grid (128, 16, 2): block handles (b, h, 16 queries). 4 waves x 4 queries/wave.
// lane = qq*16 + dg : query qq (0..3), d-group / key-group dg (0..15), 4 elems each.
__global__ __launch_bounds__(256) void attn_k(const float* __restrict__ qkv,
                                              __bf16* __restrict__ aout) {
    __shared__ float Kst[64][64];      // [d][j] transposed
    __shared__ float Vs[64][64];       // [j][d]
    __shared__ float qs[4][4][80];     // [wave][qq][d]   (pad 80: bank spread)
    __shared__ float ps[4][4][80];     // [wave][qq][j]
    int tid = threadIdx.x, wid = tid >> 6, lane = tid & 63;
    int qq = lane >> 4, dg = lane & 15;
    int h = blockIdx.y, b = blockIdx.z, kvh = h >> 2;
    int i0 = blockIdx.x * 16;
    int i = i0 + wid * 4 + qq;
    size_t rb = (size_t)b * 2048;

    f32x4 q4 = *(const f32x4*)(qkv + (rb + i) * 1536 + h * 64 + dg * 4);
    q4 *= 0.125f;  // 1/sqrt(64)
    *(f32x4*)&qs[wid][qq][dg * 4] = q4;

    f32x4 o = {0.f, 0.f, 0.f, 0.f};
    float m = -INFINITY, l = 0.f;

    int tstart = (i0 - 256) > 0 ? (i0 - 256) >> 6 : 0;
    int tmax = (i0 + 15) >> 6;
    int tt = 0;  // tile 0 = global keys [0,64), always first (guarantees finite m)
    while (true) {
        __syncthreads();
        {   // stage K (transposed) + V, coalesced 64B global segments
            int j = tid >> 2, dc = tid & 3;
            const float* kg = qkv + (rb + tt * 64 + j) * 1536 + 1024 + kvh * 64;
            const float* vg = kg + 256;
#pragma unroll
            for (int e = 0; e < 4; ++e) {
                int col = e * 16 + dc * 4;
                f32x4 kv = *(const f32x4*)(kg + col);
                Kst[col + 0][j] = kv.x; Kst[col + 1][j] = kv.y;
                Kst[col + 2][j] = kv.z; Kst[col + 3][j] = kv.w;
                *(f32x4*)&Vs[j][col] = *(const f32x4*)(vg + col);
            }
        }
        __syncthreads();

        // scores for 4 keys jj = tt*64 + dg*4 + c
        f32x4 s4 = {0.f, 0.f, 0.f, 0.f};
        const float* qrow = qs[wid][qq];
#pragma unroll 16
        for (int d = 0; d < 64; ++d)
            s4 += qrow[d] * *(const f32x4*)&Kst[d][dg * 4];

        int jbase = tt * 64 + dg * 4;
        f32x4 sv;
#pragma unroll
        for (int c = 0; c < 4; ++c) {
            int jj = jbase + c;
            bool valid = (jj <= i) && ((jj >= i - 256) || (jj < 64));
            sv[c] = valid ? s4[c] : -INFINITY;
        }
        float mx = fmaxf(fmaxf(sv.x, sv.y), fmaxf(sv.z, sv.w));
#pragma unroll
        for (int o2 = 1; o2 <= 8; o2 <<= 1) mx = fmaxf(mx, __shfl_xor(mx, o2));
        float m_new = fmaxf(m, mx);
        float alpha = __expf(m - m_new);  // finite after tile 0 (j=0 always valid)
        f32x4 p4;
#pragma unroll
        for (int c = 0; c < 4; ++c) p4[c] = __expf(sv[c] - m_new);
        float psum = p4.x + p4.y + p4.z + p4.w;
#pragma unroll
        for (int o2 = 1; o2 <= 8; o2 <<= 1) psum += __shfl_xor(psum, o2);
        l = l * alpha + psum;
        m = m_new;
        *(f32x4*)&ps[wid][qq][dg * 4] = p4;

        o *= alpha;
        const float* prow = ps[wid][qq];
#pragma unroll 16
        for (int jl = 0; jl < 64; ++jl)
            o += prow[jl] * *(const f32x4*)&Vs[jl][dg * 4];

        if (tt == 0) tt = tstart > 1 ? tstart : 1;
        else ++tt;
        if (tt > tmax) break;
    }

    f32x4 r = o * (1.0f / l);
    bf16x4 r4;
    r4.x = to_bf16(r.x); r4.y = to_bf16(r.y);
    r4.z = to_bf16(r.z); r4.w = to_bf16(r.w);
    *(bf16x4*)(aout + (rb + i) * 1024 + h * 64 + dg * 4) = r4;
}

// ---------------- launch ----------------
extern "C" void kernel_launch(void* const* d_in, const int* in_sizes, int n_in,
                              void* d_out, int out_size, void* d_ws, size_t ws_size,
                              hipStream_t stream) {
    const float* x  = (const float*)d_in[0];
    const float* wq = (const float*)d_in[1];
    const float* wk = (const float*)d_in[2];
    const float* wv = (const float*)d_in[3];
    const float* wo = (const float*)d_in[4];
    const float* gq = (const float*)d_in[5];
    const float* gk = (const float*)d_in[6];
    float* out = (float*)d_out;

    char* ws = (char*)d_ws;
    float*  qkv   = (float*)ws;                                  // 4096*1536*4 = 25165824
    __bf16* WqkvT = (__bf16*)(ws + 25165824);                    // 1536*1024*2 = 3145728
    __bf16* WoT   = (__bf16*)(ws + 25165824 + 3145728);          // 1024*1024*2 = 2097152
    __bf16* aout  = (__bf16*)(ws + 25165824 + 3145728 + 2097152);// 4096*1024*2 = 8388608

    dim3 tb(256);
    // weight transposes -> bf16 [N][K]
    transpose_k<<<dim3(32, 32), tb, 0, stream>>>(wq, WqkvT, 1024);
    transpose_k<<<dim3(32, 8),  tb, 0, stream>>>(wk, WqkvT + (size_t)1024 * 1024, 256);
    transpose_k<<<dim3(32, 8),  tb, 0, stream>>>(wv, WqkvT + (size_t)1280 * 1024, 256);
    transpose_k<<<dim3(32, 32), tb, 0, stream>>>(wo, WoT, 1024);
    // QKV projection: [4096][1536] = x[4096][1024] @ Wqkv
    gemm_bf16_k<true><<<dim3(32, 12), tb, 0, stream>>>(x, WqkvT, qkv, 1024, 1536);
    // RMSNorm + RoPE in place (q and k heads only)
    norm_rope_k<<<20480, tb, 0, stream>>>(qkv, gq, gk);
    // attention -> bf16 [4096][1024]
    attn_k<<<dim3(128, 16, 2), tb, 0, stream>>>(qkv, aout);
    // output projection: out[4096][1024] = aout @ wo
    gemm_bf16_k<false><<<dim3(32, 8), tb, 0, stream>>>(aout, WoT, out, 1024, 1024);
}

// Round 2
// 215.300 us; speedup vs baseline: 1.5544x; 1.5544x over previous
//
#include <hip/hip_runtime.h>
#include <hip/hip_bf16.h>

// ---------------- types ----------------
typedef __bf16 bf16x8 __attribute__((ext_vector_type(8)));
typedef __bf16 bf16x4 __attribute__((ext_vector_type(4)));
typedef float  f32x4  __attribute__((ext_vector_type(4)));

__device__ __forceinline__ __bf16 to_bf16(float f) {
    __hip_bfloat16 h = __float2bfloat16(f);
    return *reinterpret_cast<__bf16*>(&h);
}

// constants: B=2, L=2048, DIM=1024, H=16, KVH=4, HD=64, REP=4
// qkv row layout: [0,1024) q heads, [1024,1280) k heads, [1280,1536) v heads

// ---------------- weight transpose: src[K=1024][N] f32 -> dst[N][1024] bf16 ----
__global__ __launch_bounds__(256) void transpose_k(const float* __restrict__ src,
                                                   __bf16* __restrict__ dst, int N) {
    __shared__ float tile[32][33];
    int k0 = blockIdx.x * 32, n0 = blockIdx.y * 32;
    int tx = threadIdx.x & 31, ty = threadIdx.x >> 5;  // 32 x 8
#pragma unroll
    for (int r = 0; r < 4; ++r) {
        int kk = ty + r * 8;
        tile[kk][tx] = src[(size_t)(k0 + kk) * N + n0 + tx];
    }
    __syncthreads();
#pragma unroll
    for (int r = 0; r < 4; ++r) {
        int nn = ty + r * 8;
        dst[(size_t)(n0 + nn) * 1024 + k0 + tx] = to_bf16(tile[tx][nn]);
    }
}

// ---------------- f32 -> bf16 flat cast (8 elems/thread) ----------------
__global__ __launch_bounds__(256) void castbf_k(const float* __restrict__ src,
                                                __bf16* __restrict__ dst) {
    int i = (blockIdx.x * 256 + threadIdx.x) * 8;
    f32x4 a = *(const f32x4*)(src + i);
    f32x4 b = *(const f32x4*)(src + i + 4);
    bf16x8 h;
    h[0] = to_bf16(a.x); h[1] = to_bf16(a.y); h[2] = to_bf16(a.z); h[3] = to_bf16(a.w);
    h[4] = to_bf16(b.x); h[5] = to_bf16(b.y); h[6] = to_bf16(b.z); h[7] = to_bf16(b.w);
    *(bf16x8*)(dst + i) = h;
}

// ---------------- GEMM: C[M][N] = A[M][K] * B, A bf16 [M][K], BT bf16 [N][K] ----
__global__ __launch_bounds__(256) void gemm_bf16_k(const __bf16* __restrict__ A,
                                                   const __bf16* __restrict__ BT,
                                                   float* __restrict__ C,
                                                   int K, int N) {
    __shared__ __bf16 lA[128][40];
    __shared__ __bf16 lB[128][40];
    int tid = threadIdx.x;
    int m0 = blockIdx.x * 128;
    int n0 = blockIdx.y * 128;
    int wid = tid >> 6, lane = tid & 63;
    int wm = (wid >> 1) * 64, wn = (wid & 1) * 64;
    int lm = lane & 15, qd = lane >> 4;

    f32x4 acc[4][4] = {};

    for (int k0 = 0; k0 < K; k0 += 32) {
#pragma unroll
        for (int it = 0; it < 2; ++it) {
            int chunk = tid + it * 256;
            int row = chunk >> 2, c8 = chunk & 3;
            *(bf16x8*)&lA[row][c8 * 8] =
                *(const bf16x8*)(A + (size_t)(m0 + row) * K + k0 + c8 * 8);
            *(bf16x8*)&lB[row][c8 * 8] =
                *(const bf16x8*)(BT + (size_t)(n0 + row) * K + k0 + c8 * 8);
        }
        __syncthreads();

        bf16x8 af[4], bfr[4];
#pragma unroll
        for (int t = 0; t < 4; ++t) {
            af[t]  = *(const bf16x8*)&lA[wm + t * 16 + lm][qd * 8];
            bfr[t] = *(const bf16x8*)&lB[wn + t * 16 + lm][qd * 8];
        }
#pragma unroll
        for (int ti = 0; ti < 4; ++ti)
#pragma unroll
            for (int tj = 0; tj < 4; ++tj)
                acc[ti][tj] = __builtin_amdgcn_mfma_f32_16x16x32_bf16(
                    af[ti], bfr[tj], acc[ti][tj], 0, 0, 0);
        __syncthreads();
    }

#pragma unroll
    for (int ti = 0; ti < 4; ++ti)
#pragma unroll
        for (int tj = 0; tj < 4; ++tj)
#pragma unroll
            for (int r = 0; r < 4; ++r) {
                int row = m0 + wm + ti * 16 + qd * 4 + r;
                int col = n0 + wn + tj * 16 + lm;
                C[(size_t)row * N + col] = acc[ti][tj][r];
            }
}

// ---------------- RMSNorm + RoPE: q in-place fp32, k -> Kb bf16 ----------------
__global__ __launch_bounds__(256) void norm_rope_k(float* __restrict__ qkv,
                                                   __bf16* __restrict__ Kb,
                                                   const float* __restrict__ gq,
                                                   const float* __restrict__ gk) {
    int w = blockIdx.x * 4 + (threadIdx.x >> 6);  // 4096 tokens * 20 heads
    int lane = threadIdx.x & 63;
    int t = w / 20, hs = w % 20;
    int pos = t & 2047;
    bool isq = hs < 16;
    int col0 = isq ? hs * 64 : 1024 + (hs - 16) * 64;
    float g = isq ? gq[lane] : gk[lane];
    float* p = qkv + (size_t)t * 1536 + col0;
    float v = p[lane];
    float ss = v * v;
#pragma unroll
    for (int o = 32; o; o >>= 1) ss += __shfl_xor(ss, o);
    float scale = rsqrtf(ss * (1.0f / 64.0f) + 1e-6f);
    v = v * scale * g;
    int i2 = lane >> 1;
    float ex = (float)(2 * i2) * (1.0f / 64.0f);
    float inv = expf(-ex * 9.210340371976184f);  // theta^-(2i/64)
    float ang = (float)pos * inv;
    float c = cosf(ang), s = sinf(ang);
    float pv = __shfl_xor(v, 1);
    float out = (lane & 1) ? (pv * s + v * c) : (v * c - pv * s);
    if (isq) p[lane] = out;
    else Kb[(size_t)t * 256 + (hs - 16) * 64 + lane] = to_bf16(out);
}

// ---------------- V transpose: qkv V region -> Vt bf16 [(b*4+kvh)*64+d][2048] ----
__global__ __launch_bounds__(256) void vtrans_k(const float* __restrict__ qkv,
                                                __bf16* __restrict__ Vt) {
    __shared__ float tl[64][65];
    int g = blockIdx.y;            // b*4+kvh
    int b = g >> 2, kvh = g & 3;
    int t0 = blockIdx.x * 64;
    int tx = threadIdx.x & 63, ty = threadIdx.x >> 6;
    const float* src = qkv + ((size_t)b * 2048 + t0) * 1536 + 1280 + kvh * 64;
#pragma unroll
    for (int r = 0; r < 16; ++r) {
        int row = ty * 16 + r;
        tl[row][tx] = src[(size_t)row * 1536 + tx];
    }
    __syncthreads();
#pragma unroll
    for (int r = 0; r < 16; ++r) {
        int d = ty * 16 + r;
        Vt[((size_t)g * 64 + d) * 2048 + t0 + tx] = to_bf16(tl[tx][d]);
    }
}

// ---------------- MFMA flash attention ----------------
// grid (32, 16, 2). Block = 64 queries of head h; wave = 16 queries.
// No block-level staging, no __syncthreads. Per-wave P/O transpose buffer in LDS.
__global__ __launch_bounds__(256) void attn_k(const float* __restrict__ qkv,
                                              const __bf16* __restrict__ Kb,
                                              const __bf16* __restrict__ Vt,
                                              __bf16* __restrict__ aout) {
    __shared__ __bf16 Pb[4][16][68];   // stride 68: conflict-free b16 P-writes
    int tid = threadIdx.x, wid = tid >> 6, lane = tid & 63;
    int l15 = lane & 15, quad = lane >> 4;
    int h = blockIdx.y, b = blockIdx.z, kvh = h >> 2;
    int iw = blockIdx.x * 64 + wid * 16;      // wave's query base
    size_t tok0 = (size_t)b * 2048;

    // Q A-frags (16 queries x 64 d, two K-halves), 1/sqrt(64) baked in
    bf16x8 qf[2];
    {
        const float* qp = qkv + (tok0 + iw + l15) * 1536 + h * 64 + quad * 8;
#pragma unroll
        for (int kh = 0; kh < 2; ++kh) {
            f32x4 u = *(const f32x4*)(qp + kh * 32);
            f32x4 v = *(const f32x4*)(qp + kh * 32 + 4);
            bf16x8 q8;
            q8[0] = to_bf16(u.x * 0.125f); q8[1] = to_bf16(u.y * 0.125f);
            q8[2] = to_bf16(u.z * 0.125f); q8[3] = to_bf16(u.w * 0.125f);
            q8[4] = to_bf16(v.x * 0.125f); q8[5] = to_bf16(v.y * 0.125f);
            q8[6] = to_bf16(v.z * 0.125f); q8[7] = to_bf16(v.w * 0.125f);
            qf[kh] = q8;
        }
    }

    f32x4 o[4] = {};
    float mr[4] = {-INFINITY, -INFINITY, -INFINITY, -INFINITY};
    float lr[4] = {0.f, 0.f, 0.f, 0.f};

    int ts = (iw - 256) >> 6; if (ts < 1) ts = 1;
    int tmax = (iw + 15) >> 6;
    int nwin = (tmax >= ts) ? (tmax - ts + 1) : 0;

    for (int step = 0; step <= nwin; ++step) {
        int tt = (step == 0) ? 0 : (ts + step - 1);   // tile 0 first: finite m after it

        // ---- QK^T: 8 MFMA -> scores s[nt] (C layout: row=quad*4+r, col=nt*16+l15)
        f32x4 s[4] = {};
#pragma unroll
        for (int nt = 0; nt < 4; ++nt) {
            const __bf16* kp = Kb + (tok0 + tt * 64 + nt * 16 + l15) * 256 + kvh * 64 + quad * 8;
            s[nt] = __builtin_amdgcn_mfma_f32_16x16x32_bf16(qf[0], *(const bf16x8*)kp, s[nt], 0, 0, 0);
            s[nt] = __builtin_amdgcn_mfma_f32_16x16x32_bf16(qf[1], *(const bf16x8*)(kp + 32), s[nt], 0, 0, 0);
        }

        // ---- mask + online softmax (per query row, reduce across 16-lane quad)
        float alpha[4], p[4][4];
#pragma unroll
        for (int r = 0; r < 4; ++r) {
            int i = iw + quad * 4 + r;
            float sv[4];
            float mx = -INFINITY;
#pragma unroll
            for (int nt = 0; nt < 4; ++nt) {
                int j = tt * 64 + nt * 16 + l15;
                bool valid = (j <= i) && ((j >= i - 256) || (j < 64));
                sv[nt] = valid ? s[nt][r] : -INFINITY;
                mx = fmaxf(mx, sv[nt]);
            }
#pragma unroll
            for (int off = 1; off < 16; off <<= 1) mx = fmaxf(mx, __shfl_xor(mx, off));
            float mn = fmaxf(mr[r], mx);
            alpha[r] = __expf(mr[r] - mn);
            mr[r] = mn;
            float ps = 0.f;
#pragma unroll
            for (int nt = 0; nt < 4; ++nt) {
                float pv = __expf(sv[nt] - mn);
                p[nt][r] = pv;
                ps += pv;
            }
#pragma unroll
            for (int off = 1; off < 16; off <<= 1) ps += __shfl_xor(ps, off);
            lr[r] = lr[r] * alpha[r] + ps;
        }

        // ---- P: C layout -> A layout via per-wave LDS
#pragma unroll
        for (int nt = 0; nt < 4; ++nt)
#pragma unroll
            for (int r = 0; r < 4; ++r)
                Pb[wid][quad * 4 + r][nt * 16 + l15] = to_bf16(p[nt][r]);
        bf16x8 pf0 = *(const bf16x8*)&Pb[wid][l15][quad * 8];
        bf16x8 pf1 = *(const bf16x8*)&Pb[wid][l15][32 + quad * 8];

        // ---- rescale O, then PV: 8 MFMA
#pragma unroll
        for (int dt = 0; dt < 4; ++dt)
#pragma unroll
            for (int r = 0; r < 4; ++r) o[dt][r] *= alpha[r];
#pragma unroll
        for (int dt = 0; dt < 4; ++dt) {
            const __bf16* vp = Vt + ((size_t)(b * 4 + kvh) * 64 + dt * 16 + l15) * 2048
                               + tt * 64 + quad * 8;
            o[dt] = __builtin_amdgcn_mfma_f32_16x16x32_bf16(pf0, *(const bf16x8*)vp, o[dt], 0, 0, 0);
            o[dt] = __builtin_amdgcn_mfma_f32_16x16x32_bf16(pf1, *(const bf16x8*)(vp + 32), o[dt], 0, 0, 0);
        }
    }

    // ---- epilogue: normalize, transpose via Pb, coalesced bf16 store
    float inv[4];
#pragma unroll
    for (int r = 0; r < 4; ++r) inv[r] = 1.f / lr[r];
#pragma unroll
    for (int dt = 0; dt < 4; ++dt)
#pragma unroll
        for (int r = 0; r < 4; ++r)
            Pb[wid][quad * 4 + r][dt * 16 + l15] = to_bf16(o[dt][r] * inv[r]);
    __bf16* op = aout + (tok0 + iw + l15) * 1024 + h * 64 + quad * 16;
    bf16x8 o0 = *(const bf16x8*)&Pb[wid][l15][quad * 16];
    bf16x8 o1 = *(const bf16x8*)&Pb[wid][l15][quad * 16 + 8];
    *(bf16x8*)op = o0;
    *(bf16x8*)(op + 8) = o1;
}

// ---------------- launch ----------------
extern "C" void kernel_launch(void* const* d_in, const int* in_sizes, int n_in,
                              void* d_out, int out_size, void* d_ws, size_t ws_size,
                              hipStream_t stream) {
    const float* x  = (const float*)d_in[0];
    const float* wq = (const float*)d_in[1];
    const float* wk = (const float*)d_in[2];
    const float* wv = (const float*)d_in[3];
    const float* wo = (const float*)d_in[4];
    const float* gq = (const float*)d_in[5];
    const float* gk = (const float*)d_in[6];
    float* out = (float*)d_out;

    char* ws = (char*)d_ws;
    float*  qkv   = (float*)ws;                          // 25165824 B
    __bf16* WqkvT = (__bf16*)(ws + 25165824);            //  3145728 B
    __bf16* WoT   = (__bf16*)(ws + 28311552);            //  2097152 B
    __bf16* xb_ao = (__bf16*)(ws + 30408704);            //  8388608 B (xb, then aout)
    __bf16* Kb    = (__bf16*)(ws + 38797312);            //  2097152 B
    __bf16* Vt    = (__bf16*)(ws + 40894464);            //  2097152 B  -> total 42991616

    dim3 tb(256);
    transpose_k<<<dim3(32, 32), tb, 0, stream>>>(wq, WqkvT, 1024);
    transpose_k<<<dim3(32, 8),  tb, 0, stream>>>(wk, WqkvT + (size_t)1024 * 1024, 256);
    transpose_k<<<dim3(32, 8),  tb, 0, stream>>>(wv, WqkvT + (size_t)1280 * 1024, 256);
    transpose_k<<<dim3(32, 32), tb, 0, stream>>>(wo, WoT, 1024);
    castbf_k<<<2048, tb, 0, stream>>>(x, xb_ao);                         // x -> bf16
    gemm_bf16_k<<<dim3(32, 12), tb, 0, stream>>>(xb_ao, WqkvT, qkv, 1024, 1536);
    norm_rope_k<<<20480, tb, 0, stream>>>(qkv, Kb, gq, gk);
    vtrans_k<<<dim3(32, 8), tb, 0, stream>>>(qkv, Vt);
    attn_k<<<dim3(32, 16, 2), tb, 0, stream>>>(qkv, Kb, Vt, xb_ao);      // aout reuses xb
    gemm_bf16_k<<<dim3(32, 8), tb, 0, stream>>>(xb_ao, WoT, out, 1024, 1024);
}